// Round 5
// baseline (85.882 us; speedup 1.0000x reference)
//
#include <hip/hip_runtime.h>
#include <stdint.h>

#define BB 16
#define SS 10
#define CLSN 4
#define FGN 3
#define HH 192
#define WW 192
#define NPIX (HH * WW)    // 36864
#define WPR 3             // u64 words per row
#define NWORDS (HH * WPR) // 576
#define NPAIR (BB * SS)   // 160
#define NTASK (NPAIR * FGN) // 480

#define K1_BLOCKS 1440
#define K1_THREADS 256
#define K1_WAVES (K1_BLOCKS * 4)                  // 5760
#define K1_CHUNK ((NPAIR * NWORDS) / K1_WAVES)    // 16

typedef unsigned long long u64;

// full adder: s = a^b^c, cy = majority(a,b,c)
#define FAD(a, b, c, s, cy)            \
    do {                               \
        u64 t_ = (a) ^ (b);            \
        (s) = t_ ^ (c);                \
        (cy) = ((a) & (b)) | (t_ & (c)); \
    } while (0)

// horizontal +/-1 smear of a 3-word row (192 bits)
#define SMEAR3(u0, u1, u2, s0, s1, s2)                          \
    do {                                                        \
        (s0) = (u0) | ((u0) << 1) | ((u0) >> 1) | ((u1) << 63); \
        (s1) = (u1) | ((u1) << 1) | ((u0) >> 63) | ((u1) >> 1) | ((u2) << 63); \
        (s2) = (u2) | ((u2) << 1) | ((u1) >> 63) | ((u2) >> 1); \
    } while (0)

// bit-sliced 3x3 ones-conv of bitboard `bd` at word k: 4 count bit-planes + center
__device__ __forceinline__ void plane9(const u64* bd, int k,
                                       u64& P0, u64& P1, u64& P2, u64& P3, u64& mid)
{
    const int r = k / WPR;
    const int wc = k - r * WPR;
    u64 rows[3][3];
#pragma unroll
    for (int di = 0; di < 3; ++di) {
        int rr = r + di - 1;
#pragma unroll
        for (int dj = 0; dj < 3; ++dj) {
            int ww = wc + dj - 1;
            rows[di][dj] = (rr >= 0 && rr < HH && ww >= 0 && ww < WPR)
                           ? bd[rr * WPR + ww] : 0ULL;
        }
    }
    mid = rows[1][1];
    u64 in[9];
#pragma unroll
    for (int i = 0; i < 3; ++i) {
        u64 m = rows[i][1], lf = rows[i][0], rg = rows[i][2];
        in[3 * i + 0] = m;
        in[3 * i + 1] = (m << 1) | (lf >> 63);
        in[3 * i + 2] = (m >> 1) | (rg << 63);
    }
    u64 s0a, c0a, s0b, c0b, s0c, c0c, c0d, s1a, c1a, c1b;
    FAD(in[0], in[1], in[2], s0a, c0a);
    FAD(in[3], in[4], in[5], s0b, c0b);
    FAD(in[6], in[7], in[8], s0c, c0c);
    FAD(s0a, s0b, s0c, P0, c0d);
    FAD(c0a, c0b, c0c, s1a, c1a);
    P1 = s1a ^ c0d;
    c1b = s1a & c0d;
    P2 = c1a ^ c1b;
    P3 = c1a & c1b;
}

// ============================================================================
// K1: dense pass. Per (pair, word): build 3 class bitboard words -> fgAll,
// accumulate dense term -sum_{v>0} log(preds[b,v,pix]+1e-8).
// ============================================================================
__global__ __launch_bounds__(K1_THREADS) void k1_dense(
    const float* __restrict__ preds,
    const int* __restrict__ samples,
    u64* __restrict__ fgAll,
    double* __restrict__ acc)
{
    __shared__ double wsum[4];
    const int tid  = threadIdx.x;
    const int lane = tid & 63;
    const int wv   = tid >> 6;
    const int wid  = blockIdx.x * 4 + wv;

    float facc = 0.0f;
    const int base = wid * K1_CHUNK;
#pragma unroll 4
    for (int i = 0; i < K1_CHUNK; ++i) {
        const int t = base + i;
        const int pair = t / NWORDS;
        const int word = t - pair * NWORDS;
        const int b = pair / SS;
        const int pix = (word << 6) + lane;
        const int v = samples[(size_t)pair * NPIX + pix];
        const float p = preds[((size_t)b * CLSN + v) * NPIX + pix];
        u64 m1 = __ballot(v == 1);
        u64 m2 = __ballot(v == 2);
        u64 m3 = __ballot(v == 3);
        if (lane == 0) {
            fgAll[(size_t)(0 * NPAIR + pair) * NWORDS + word] = m1;
            fgAll[(size_t)(1 * NPAIR + pair) * NWORDS + word] = m2;
            fgAll[(size_t)(2 * NPAIR + pair) * NWORDS + word] = m3;
        }
        float lp = __logf(p + 1e-8f);
        facc -= (v > 0) ? lp : 0.0f;
    }
#pragma unroll
    for (int off = 32; off > 0; off >>= 1)
        facc += __shfl_xor(facc, off, 64);
    if (lane == 0) wsum[wv] = (double)facc;
    __syncthreads();
    if (tid == 0)
        atomicAdd(acc, wsum[0] + wsum[1] + wsum[2] + wsum[3]);
}

// ============================================================================
// K2: per-task (480 blocks x 1 wave): seed argmax, register flood fill,
// correction term +sum_comp (cnt/9+1)*log(p).
// ============================================================================
__global__ __launch_bounds__(64) void k2_comp(
    const float* __restrict__ preds,
    const u64* __restrict__ fgAll,
    double* __restrict__ acc)
{
    __shared__ u64 fgw[NWORDS];
    __shared__ u64 cmp[NWORDS];

    const int blk  = blockIdx.x;
    const int c    = 1 + blk / NPAIR;
    const int pair = blk % NPAIR;
    const int b    = pair / SS;
    const int lane = threadIdx.x;

    // stage fg bitboard (coalesced)
    const u64* fgsrc = fgAll + (size_t)blk * NWORDS;
#pragma unroll
    for (int i = 0; i < 9; ++i)
        fgw[lane + 64 * i] = fgsrc[lane + 64 * i];
    __syncthreads();

    // ---- seed argmax (first-max tie-break) ----
    unsigned int bestkey = 0u;
#pragma unroll
    for (int i = 0; i < 9; ++i) {
        const int k = lane + 64 * i;
        u64 P0, P1, P2, P3, mid;
        plane9(fgw, k, P0, P1, P2, P3, mid);
        if (mid) {
            u64 cand = mid, t;
            unsigned v = 0;
            t = cand & P3; if (t) { cand = t; v |= 8u; }
            t = cand & P2; if (t) { cand = t; v |= 4u; }
            t = cand & P1; if (t) { cand = t; v |= 2u; }
            t = cand & P0; if (t) { cand = t; v |= 1u; }
            unsigned pix = ((unsigned)k << 6) + (unsigned)(__ffsll(cand) - 1);
            unsigned key = (v << 16) | (36863u - pix);
            if (key > bestkey) bestkey = key;
        }
    }
#pragma unroll
    for (int off = 32; off > 0; off >>= 1) {
        unsigned int o = (unsigned int)__shfl_xor((int)bestkey, off, 64);
        if (o > bestkey) bestkey = o;
    }
    const unsigned seed = 36863u - (bestkey & 0xFFFFu);  // all lanes agree

    // ---- register flood fill: lane l owns rows 3l..3l+2 ----
    u64 f[3][3], cc[3][3];
#pragma unroll
    for (int j = 0; j < 3; ++j)
#pragma unroll
        for (int w = 0; w < 3; ++w) {
            f[j][w] = fgw[(3 * lane + j) * WPR + w];
            cc[j][w] = 0ULL;
        }
    {
        const int sr = (int)(seed / WW), sw = ((int)seed % WW) >> 6, sb = (int)seed & 63;
        if (sr / 3 == lane)
            cc[sr % 3][sw] = (1ULL << sb) & f[sr % 3][sw];
    }
    for (;;) {
        u64 bA0 = __shfl_up(cc[2][0], 1, 64);
        u64 bA1 = __shfl_up(cc[2][1], 1, 64);
        u64 bA2 = __shfl_up(cc[2][2], 1, 64);
        u64 tB0 = __shfl_down(cc[0][0], 1, 64);
        u64 tB1 = __shfl_down(cc[0][1], 1, 64);
        u64 tB2 = __shfl_down(cc[0][2], 1, 64);
        if (lane == 0)  { bA0 = bA1 = bA2 = 0ULL; }
        if (lane == 63) { tB0 = tB1 = tB2 = 0ULL; }

        u64 o00 = cc[0][0], o01 = cc[0][1], o02 = cc[0][2];
        u64 o10 = cc[1][0], o11 = cc[1][1], o12 = cc[1][2];
        u64 o20 = cc[2][0], o21 = cc[2][1], o22 = cc[2][2];

        u64 u0, u1, u2, s0, s1, s2;
        // down pass
        u0 = bA0 | cc[0][0] | cc[1][0]; u1 = bA1 | cc[0][1] | cc[1][1]; u2 = bA2 | cc[0][2] | cc[1][2];
        SMEAR3(u0, u1, u2, s0, s1, s2);
        cc[0][0] = s0 & f[0][0]; cc[0][1] = s1 & f[0][1]; cc[0][2] = s2 & f[0][2];

        u0 = cc[0][0] | cc[1][0] | cc[2][0]; u1 = cc[0][1] | cc[1][1] | cc[2][1]; u2 = cc[0][2] | cc[1][2] | cc[2][2];
        SMEAR3(u0, u1, u2, s0, s1, s2);
        cc[1][0] = s0 & f[1][0]; cc[1][1] = s1 & f[1][1]; cc[1][2] = s2 & f[1][2];

        u0 = cc[1][0] | cc[2][0] | tB0; u1 = cc[1][1] | cc[2][1] | tB1; u2 = cc[1][2] | cc[2][2] | tB2;
        SMEAR3(u0, u1, u2, s0, s1, s2);
        cc[2][0] = s0 & f[2][0]; cc[2][1] = s1 & f[2][1]; cc[2][2] = s2 & f[2][2];

        // up pass
        u0 = cc[0][0] | cc[1][0] | cc[2][0]; u1 = cc[0][1] | cc[1][1] | cc[2][1]; u2 = cc[0][2] | cc[1][2] | cc[2][2];
        SMEAR3(u0, u1, u2, s0, s1, s2);
        cc[1][0] = s0 & f[1][0]; cc[1][1] = s1 & f[1][1]; cc[1][2] = s2 & f[1][2];

        u0 = bA0 | cc[0][0] | cc[1][0]; u1 = bA1 | cc[0][1] | cc[1][1]; u2 = bA2 | cc[0][2] | cc[1][2];
        SMEAR3(u0, u1, u2, s0, s1, s2);
        cc[0][0] = s0 & f[0][0]; cc[0][1] = s1 & f[0][1]; cc[0][2] = s2 & f[0][2];

        u64 d = (cc[0][0] ^ o00) | (cc[0][1] ^ o01) | (cc[0][2] ^ o02)
              | (cc[1][0] ^ o10) | (cc[1][1] ^ o11) | (cc[1][2] ^ o12)
              | (cc[2][0] ^ o20) | (cc[2][1] ^ o21) | (cc[2][2] ^ o22);
        if (!__any(d != 0ULL)) break;
    }

    // publish comp to LDS
#pragma unroll
    for (int j = 0; j < 3; ++j)
#pragma unroll
        for (int w = 0; w < 3; ++w)
            cmp[(3 * lane + j) * WPR + w] = cc[j][w];
    __syncthreads();

    // ---- correction: visit only nonempty comp words ----
    float facc = 0.0f;
    const float* pp = preds + ((size_t)b * CLSN + c) * NPIX;
#pragma unroll
    for (int jw = 0; jw < 9; ++jw) {
        const int j = jw / 3, w = jw - 3 * (jw / 3);
        u64 m = __ballot(cc[j][w] != 0ULL);   // wave-uniform mask of owning lanes
        while (m) {
            const int src = (int)(__ffsll(m) - 1);
            m &= m - 1;
            const int k = 9 * src + jw;       // (3*src+j)*3+w
            u64 P0, P1, P2, P3, mid;
            plane9(cmp, k, P0, P1, P2, P3, mid);
            if ((mid >> lane) & 1ULL) {
                int cnt = (int)((P0 >> lane) & 1ULL)
                        | ((int)((P1 >> lane) & 1ULL) << 1)
                        | ((int)((P2 >> lane) & 1ULL) << 2)
                        | ((int)((P3 >> lane) & 1ULL) << 3);
                float lp = __logf(pp[(k << 6) + lane] + 1e-8f);
                facc += ((float)cnt * (1.0f / 9.0f) + 1.0f) * lp;
            }
        }
    }
#pragma unroll
    for (int off = 32; off > 0; off >>= 1)
        facc += __shfl_xor(facc, off, 64);
    if (lane == 0)
        atomicAdd(acc, (double)facc);
}

// ============================================================================
// Fallback fused kernel (round-4 structure) if ws is too small for bitboards.
// ============================================================================
__global__ __launch_bounds__(512) void cc_loss_fused(
    const float* __restrict__ preds,
    const int* __restrict__ samples,
    double* __restrict__ acc)
{
    __shared__ u64 fgw[NWORDS];
    __shared__ u64 compB[NWORDS];
    __shared__ unsigned int wkey[8];
    __shared__ double wsum[8];
    __shared__ unsigned int seedIdx;

    const int blk = blockIdx.x;
    const int c = 1 + blk / NPAIR;
    const int pair = blk % NPAIR;
    const int b = pair / SS;

    const int tid  = threadIdx.x;
    const int lane = tid & 63;
    const int wv   = tid >> 6;

    const int* smp = samples + (size_t)pair * NPIX;
    const float* pp = preds + ((size_t)b * CLSN + c) * NPIX;

    float facc = 0.0f;
    {
        const int base = wv * 72;
        for (int i = 0; i < 72; i += 6) {
            int v[6]; float pv[6];
#pragma unroll
            for (int j = 0; j < 6; ++j) {
                int pix = ((base + i + j) << 6) + lane;
                v[j]  = smp[pix];
                pv[j] = pp[pix];
            }
#pragma unroll
            for (int j = 0; j < 6; ++j) {
                u64 m = __ballot(v[j] == c);
                if (lane == 0) fgw[base + i + j] = m;
                float lp = __logf(pv[j] + 1e-8f);
                facc -= (v[j] == c) ? lp : 0.0f;
            }
        }
    }
    __syncthreads();
    {
        unsigned int bestkey = 0u;
        for (int k = tid; k < NWORDS; k += 512) {
            u64 P0, P1, P2, P3, mid;
            plane9(fgw, k, P0, P1, P2, P3, mid);
            if (mid) {
                u64 cand = mid, t;
                unsigned v = 0;
                t = cand & P3; if (t) { cand = t; v |= 8u; }
                t = cand & P2; if (t) { cand = t; v |= 4u; }
                t = cand & P1; if (t) { cand = t; v |= 2u; }
                t = cand & P0; if (t) { cand = t; v |= 1u; }
                unsigned pix = ((unsigned)k << 6) + (unsigned)(__ffsll(cand) - 1);
                unsigned key = (v << 16) | (36863u - pix);
                if (key > bestkey) bestkey = key;
            }
        }
#pragma unroll
        for (int off = 32; off > 0; off >>= 1) {
            unsigned int o = (unsigned int)__shfl_xor((int)bestkey, off, 64);
            if (o > bestkey) bestkey = o;
        }
        if (lane == 0) wkey[wv] = bestkey;
    }
    __syncthreads();
    if (tid == 0) {
        unsigned int kk = 0u;
#pragma unroll
        for (int i = 0; i < 8; ++i)
            if (wkey[i] > kk) kk = wkey[i];
        seedIdx = 36863u - (kk & 0xFFFFu);
    }
    __syncthreads();
    if (wv == 0) {
        const unsigned seed = seedIdx;
        u64 f[3][3], cc[3][3];
        const int rbase = 3 * lane;
#pragma unroll
        for (int j = 0; j < 3; ++j)
#pragma unroll
            for (int w = 0; w < 3; ++w) {
                f[j][w] = fgw[(rbase + j) * WPR + w];
                cc[j][w] = 0ULL;
            }
        {
            const int sr = seed / WW, sw = (seed % WW) >> 6, sb = seed & 63;
            if (sr / 3 == lane)
                cc[sr % 3][sw] = (1ULL << sb) & f[sr % 3][sw];
        }
        for (;;) {
            u64 bA0 = __shfl_up(cc[2][0], 1, 64);
            u64 bA1 = __shfl_up(cc[2][1], 1, 64);
            u64 bA2 = __shfl_up(cc[2][2], 1, 64);
            u64 tB0 = __shfl_down(cc[0][0], 1, 64);
            u64 tB1 = __shfl_down(cc[0][1], 1, 64);
            u64 tB2 = __shfl_down(cc[0][2], 1, 64);
            if (lane == 0)  { bA0 = bA1 = bA2 = 0ULL; }
            if (lane == 63) { tB0 = tB1 = tB2 = 0ULL; }
            u64 o00 = cc[0][0], o01 = cc[0][1], o02 = cc[0][2];
            u64 o10 = cc[1][0], o11 = cc[1][1], o12 = cc[1][2];
            u64 o20 = cc[2][0], o21 = cc[2][1], o22 = cc[2][2];
            u64 u0, u1, u2, s0, s1, s2;
            u0 = bA0 | cc[0][0] | cc[1][0]; u1 = bA1 | cc[0][1] | cc[1][1]; u2 = bA2 | cc[0][2] | cc[1][2];
            SMEAR3(u0, u1, u2, s0, s1, s2);
            cc[0][0] = s0 & f[0][0]; cc[0][1] = s1 & f[0][1]; cc[0][2] = s2 & f[0][2];
            u0 = cc[0][0] | cc[1][0] | cc[2][0]; u1 = cc[0][1] | cc[1][1] | cc[2][1]; u2 = cc[0][2] | cc[1][2] | cc[2][2];
            SMEAR3(u0, u1, u2, s0, s1, s2);
            cc[1][0] = s0 & f[1][0]; cc[1][1] = s1 & f[1][1]; cc[1][2] = s2 & f[1][2];
            u0 = cc[1][0] | cc[2][0] | tB0; u1 = cc[1][1] | cc[2][1] | tB1; u2 = cc[1][2] | cc[2][2] | tB2;
            SMEAR3(u0, u1, u2, s0, s1, s2);
            cc[2][0] = s0 & f[2][0]; cc[2][1] = s1 & f[2][1]; cc[2][2] = s2 & f[2][2];
            u0 = cc[0][0] | cc[1][0] | cc[2][0]; u1 = cc[0][1] | cc[1][1] | cc[2][1]; u2 = cc[0][2] | cc[1][2] | cc[2][2];
            SMEAR3(u0, u1, u2, s0, s1, s2);
            cc[1][0] = s0 & f[1][0]; cc[1][1] = s1 & f[1][1]; cc[1][2] = s2 & f[1][2];
            u0 = bA0 | cc[0][0] | cc[1][0]; u1 = bA1 | cc[0][1] | cc[1][1]; u2 = bA2 | cc[0][2] | cc[1][2];
            SMEAR3(u0, u1, u2, s0, s1, s2);
            cc[0][0] = s0 & f[0][0]; cc[0][1] = s1 & f[0][1]; cc[0][2] = s2 & f[0][2];
            u64 d = (cc[0][0] ^ o00) | (cc[0][1] ^ o01) | (cc[0][2] ^ o02)
                  | (cc[1][0] ^ o10) | (cc[1][1] ^ o11) | (cc[1][2] ^ o12)
                  | (cc[2][0] ^ o20) | (cc[2][1] ^ o21) | (cc[2][2] ^ o22);
            if (!__any(d != 0ULL)) break;
        }
#pragma unroll
        for (int j = 0; j < 3; ++j)
#pragma unroll
            for (int w = 0; w < 3; ++w)
                compB[(rbase + j) * WPR + w] = cc[j][w];
    }
    __syncthreads();
    {
        const int base = wv * 72;
        for (int k = base; k < base + 72; ++k) {
            u64 cw = compB[k];
            if (cw == 0ULL) continue;
            u64 P0, P1, P2, P3, mid;
            plane9(compB, k, P0, P1, P2, P3, mid);
            if ((cw >> lane) & 1ULL) {
                int cnt = (int)((P0 >> lane) & 1ULL)
                        | ((int)((P1 >> lane) & 1ULL) << 1)
                        | ((int)((P2 >> lane) & 1ULL) << 2)
                        | ((int)((P3 >> lane) & 1ULL) << 3);
                float lp = __logf(pp[(k << 6) + lane] + 1e-8f);
                facc += ((float)cnt * (1.0f / 9.0f) + 1.0f) * lp;
            }
        }
    }
#pragma unroll
    for (int off = 32; off > 0; off >>= 1)
        facc += __shfl_xor(facc, off, 64);
    if (lane == 0) wsum[wv] = (double)facc;
    __syncthreads();
    if (tid == 0) {
        double t = 0.0;
#pragma unroll
        for (int i = 0; i < 8; ++i) t += wsum[i];
        atomicAdd(acc, t);
    }
}

__global__ void finalize_kernel(const double* __restrict__ acc, float* __restrict__ out)
{
    if (threadIdx.x == 0 && blockIdx.x == 0)
        out[0] = (float)(-acc[0] / (double)((long long)BB * SS * NPIX));
}

extern "C" void kernel_launch(void* const* d_in, const int* in_sizes, int n_in,
                              void* d_out, int out_size, void* d_ws, size_t ws_size,
                              hipStream_t stream)
{
    const float* preds   = (const float*)d_in[0];
    const int*   samples = (const int*)d_in[1];

    const size_t fg_bytes = (size_t)NTASK * NWORDS * sizeof(u64);  // 2,211,840
    if (ws_size >= fg_bytes + sizeof(double)) {
        u64* fgAll  = (u64*)d_ws;
        double* acc = (double*)((char*)d_ws + fg_bytes);
        hipMemsetAsync(acc, 0, sizeof(double), stream);
        hipLaunchKernelGGL(k1_dense, dim3(K1_BLOCKS), dim3(K1_THREADS), 0, stream,
                           preds, samples, fgAll, acc);
        hipLaunchKernelGGL(k2_comp, dim3(NTASK), dim3(64), 0, stream,
                           preds, fgAll, acc);
        hipLaunchKernelGGL(finalize_kernel, dim3(1), dim3(64), 0, stream,
                           acc, (float*)d_out);
    } else {
        double* acc = (double*)d_ws;
        hipMemsetAsync(acc, 0, sizeof(double), stream);
        hipLaunchKernelGGL(cc_loss_fused, dim3(NTASK), dim3(512), 0, stream,
                           preds, samples, acc);
        hipLaunchKernelGGL(finalize_kernel, dim3(1), dim3(64), 0, stream,
                           acc, (float*)d_out);
    }
}

// Round 6
// 49.346 us; speedup vs baseline: 1.7404x; 1.7404x over previous
//
#include <hip/hip_runtime.h>
#include <stdint.h>

#define BB 16
#define SS 10
#define CLSN 4
#define FGN 3
#define HH 192
#define WW 192
#define NPIX (HH * WW)    // 36864
#define WPR 3             // u64 words per row
#define NWORDS (HH * WPR) // 576
#define NPAIR (BB * SS)   // 160
#define NTASK (NPAIR * FGN) // 480
#define NT 256
#define NW 4

typedef unsigned long long u64;
typedef unsigned short u16;

// full adder: s = a^b^c, cy = majority(a,b,c)
#define FAD(a, b, c, s, cy)            \
    do {                               \
        u64 t_ = (a) ^ (b);            \
        (s) = t_ ^ (c);                \
        (cy) = ((a) & (b)) | (t_ & (c)); \
    } while (0)

// horizontal +/-1 smear of a 3-word row (192 bits)
#define SMEAR3(u0, u1, u2, s0, s1, s2)                          \
    do {                                                        \
        (s0) = (u0) | ((u0) << 1) | ((u0) >> 1) | ((u1) << 63); \
        (s1) = (u1) | ((u1) << 1) | ((u0) >> 63) | ((u1) >> 1) | ((u2) << 63); \
        (s2) = (u2) | ((u2) << 1) | ((u1) >> 63) | ((u2) >> 1); \
    } while (0)

// bit-sliced 3x3 ones-conv of bitboard `bd` at word k: 4 count bit-planes + center
__device__ __forceinline__ void plane9(const u64* bd, int k,
                                       u64& P0, u64& P1, u64& P2, u64& P3, u64& mid)
{
    const int r = k / WPR;
    const int wc = k - r * WPR;
    u64 rows[3][3];
#pragma unroll
    for (int di = 0; di < 3; ++di) {
        int rr = r + di - 1;
#pragma unroll
        for (int dj = 0; dj < 3; ++dj) {
            int ww = wc + dj - 1;
            rows[di][dj] = (rr >= 0 && rr < HH && ww >= 0 && ww < WPR)
                           ? bd[rr * WPR + ww] : 0ULL;
        }
    }
    mid = rows[1][1];
    u64 in[9];
#pragma unroll
    for (int i = 0; i < 3; ++i) {
        u64 m = rows[i][1], lf = rows[i][0], rg = rows[i][2];
        in[3 * i + 0] = m;
        in[3 * i + 1] = (m << 1) | (lf >> 63);
        in[3 * i + 2] = (m >> 1) | (rg << 63);
    }
    u64 s0a, c0a, s0b, c0b, s0c, c0c, c0d, s1a, c1a, c1b;
    FAD(in[0], in[1], in[2], s0a, c0a);
    FAD(in[3], in[4], in[5], s0b, c0b);
    FAD(in[6], in[7], in[8], s0c, c0c);
    FAD(s0a, s0b, s0c, P0, c0d);
    FAD(c0a, c0b, c0c, s1a, c1a);
    P1 = s1a ^ c0d;
    c1b = s1a & c0d;
    P2 = c1a ^ c1b;
    P3 = c1a & c1b;
}

__global__ __launch_bounds__(NT) void cc_fused(
    const float* __restrict__ preds,
    const int* __restrict__ samples,
    double* __restrict__ acc)
{
    __shared__ u64 fgw[NWORDS];   // built via u16 nibble alias (zero repack)
    __shared__ u64 cmp[NWORDS];
    __shared__ unsigned wkey[NW];
    __shared__ double wsum[NW];
    __shared__ unsigned seedSh;
    __shared__ int cntSh;
    __shared__ short wlist[NWORDS];

    // XCD-locality mapping: the 3 class-tasks of one (b,s) are 160 apart;
    // 160 % 8 == 0 -> same XCD -> samples L2 reuse.
    const int blk = blockIdx.x;
    const int c = 1 + blk / NPAIR;
    const int pair = blk % NPAIR;
    const int b = pair / SS;

    const int tid  = threadIdx.x;
    const int lane = tid & 63;
    const int wv   = tid >> 6;

    const int* __restrict__ smp  = samples + (size_t)pair * NPIX;
    const float* __restrict__ pp = preds + ((size_t)b * CLSN + c) * NPIX;

    if (tid == 0) cntSh = 0;

    float facc = 0.0f;

    // ---- Phase A: int4/float4 loads; 16-px mask nibble -> LDS u16.
    // u16[4k..4k+3] little-endian == u64 word k, so fgw builds itself.
    // Fused dense term: -sum_{v==c} log(p + 1e-8).
    {
        u16* nib = (u16*)fgw;
        for (int sc = 0; sc < 9; ++sc) {
            const int ci = sc * NT + tid;
            const int px = ci << 4;
            const int4 v0 = *(const int4*)(smp + px);
            const int4 v1 = *(const int4*)(smp + px + 4);
            const int4 v2 = *(const int4*)(smp + px + 8);
            const int4 v3 = *(const int4*)(smp + px + 12);
            const float4 q0 = *(const float4*)(pp + px);
            const float4 q1 = *(const float4*)(pp + px + 4);
            const float4 q2 = *(const float4*)(pp + px + 8);
            const float4 q3 = *(const float4*)(pp + px + 12);
            unsigned m = 0u;
#define ACC1(vv, qq, sh)                                              \
            {                                                          \
                const bool hit_ = ((vv) == c);                         \
                m |= ((unsigned)hit_) << (sh);                         \
                facc -= hit_ ? __logf((qq) + 1e-8f) : 0.0f;            \
            }
            ACC1(v0.x, q0.x, 0)  ACC1(v0.y, q0.y, 1)
            ACC1(v0.z, q0.z, 2)  ACC1(v0.w, q0.w, 3)
            ACC1(v1.x, q1.x, 4)  ACC1(v1.y, q1.y, 5)
            ACC1(v1.z, q1.z, 6)  ACC1(v1.w, q1.w, 7)
            ACC1(v2.x, q2.x, 8)  ACC1(v2.y, q2.y, 9)
            ACC1(v2.z, q2.z, 10) ACC1(v2.w, q2.w, 11)
            ACC1(v3.x, q3.x, 12) ACC1(v3.y, q3.y, 13)
            ACC1(v3.z, q3.z, 14) ACC1(v3.w, q3.w, 15)
#undef ACC1
            nib[ci] = (u16)m;
        }
    }
    __syncthreads();

    // ---- Phase B: bit-sliced neighbor counts -> argmax seed (first-max tie-break) ----
    {
        unsigned bestkey = 0u;
        for (int k = tid; k < NWORDS; k += NT) {
            u64 P0, P1, P2, P3, mid;
            plane9(fgw, k, P0, P1, P2, P3, mid);
            if (mid) {
                u64 cand = mid, t;
                unsigned v = 0;
                t = cand & P3; if (t) { cand = t; v |= 8u; }
                t = cand & P2; if (t) { cand = t; v |= 4u; }
                t = cand & P1; if (t) { cand = t; v |= 2u; }
                t = cand & P0; if (t) { cand = t; v |= 1u; }
                unsigned pix = ((unsigned)k << 6) + (unsigned)(__ffsll(cand) - 1);
                unsigned key = (v << 16) | (36863u - pix);
                if (key > bestkey) bestkey = key;
            }
        }
#pragma unroll
        for (int off = 32; off > 0; off >>= 1) {
            unsigned o = (unsigned)__shfl_xor((int)bestkey, off, 64);
            if (o > bestkey) bestkey = o;
        }
        if (lane == 0) wkey[wv] = bestkey;
    }
    __syncthreads();
    if (tid == 0) {
        unsigned kk = wkey[0];
        if (wkey[1] > kk) kk = wkey[1];
        if (wkey[2] > kk) kk = wkey[2];
        if (wkey[3] > kk) kk = wkey[3];
        seedSh = 36863u - (kk & 0xFFFFu);
    }
    __syncthreads();

    // ---- Phase C: register flood fill on wave 0, +/-2 gap-safe smear per row-step ----
    if (wv == 0) {
        const unsigned seed = seedSh;
        u64 f[3][3], cc[3][3];
        const int rbase = 3 * lane;
#pragma unroll
        for (int j = 0; j < 3; ++j)
#pragma unroll
            for (int w = 0; w < 3; ++w) {
                f[j][w] = fgw[(rbase + j) * WPR + w];
                cc[j][w] = 0ULL;
            }
        {
            const int sr = (int)(seed / WW), sw = ((int)seed % WW) >> 6, sb = (int)seed & 63;
            if (sr / 3 == lane)
                cc[sr % 3][sw] = (1ULL << sb) & f[sr % 3][sw];
        }
        for (;;) {
            u64 bA0 = __shfl_up(cc[2][0], 1, 64);
            u64 bA1 = __shfl_up(cc[2][1], 1, 64);
            u64 bA2 = __shfl_up(cc[2][2], 1, 64);
            u64 tB0 = __shfl_down(cc[0][0], 1, 64);
            u64 tB1 = __shfl_down(cc[0][1], 1, 64);
            u64 tB2 = __shfl_down(cc[0][2], 1, 64);
            if (lane == 0)  { bA0 = bA1 = bA2 = 0ULL; }
            if (lane == 63) { tB0 = tB1 = tB2 = 0ULL; }

            u64 o00 = cc[0][0], o01 = cc[0][1], o02 = cc[0][2];
            u64 o10 = cc[1][0], o11 = cc[1][1], o12 = cc[1][2];
            u64 o20 = cc[2][0], o21 = cc[2][1], o22 = cc[2][2];

            // row-step: vertical OR, then (smear & f) twice -> +/-2 reach, gap-safe
#define RSTEP(A0, A1, A2, B0, B1, B2, C0, C1, C2, J)                          \
            {                                                                  \
                u64 u0 = (A0) | (B0) | (C0);                                   \
                u64 u1 = (A1) | (B1) | (C1);                                   \
                u64 u2 = (A2) | (B2) | (C2);                                   \
                u64 t0, t1, t2, s0, s1, s2;                                    \
                SMEAR3(u0, u1, u2, t0, t1, t2);                                \
                t0 &= f[J][0]; t1 &= f[J][1]; t2 &= f[J][2];                   \
                SMEAR3(t0, t1, t2, s0, s1, s2);                                \
                cc[J][0] = s0 & f[J][0];                                       \
                cc[J][1] = s1 & f[J][1];                                       \
                cc[J][2] = s2 & f[J][2];                                       \
            }
            // down pass (Gauss-Seidel within lane's 3 rows)
            RSTEP(bA0, bA1, bA2, cc[0][0], cc[0][1], cc[0][2], cc[1][0], cc[1][1], cc[1][2], 0)
            RSTEP(cc[0][0], cc[0][1], cc[0][2], cc[1][0], cc[1][1], cc[1][2], cc[2][0], cc[2][1], cc[2][2], 1)
            RSTEP(cc[1][0], cc[1][1], cc[1][2], cc[2][0], cc[2][1], cc[2][2], tB0, tB1, tB2, 2)
            // up pass
            RSTEP(cc[0][0], cc[0][1], cc[0][2], cc[1][0], cc[1][1], cc[1][2], cc[2][0], cc[2][1], cc[2][2], 1)
            RSTEP(bA0, bA1, bA2, cc[0][0], cc[0][1], cc[0][2], cc[1][0], cc[1][1], cc[1][2], 0)
#undef RSTEP

            u64 d = (cc[0][0] ^ o00) | (cc[0][1] ^ o01) | (cc[0][2] ^ o02)
                  | (cc[1][0] ^ o10) | (cc[1][1] ^ o11) | (cc[1][2] ^ o12)
                  | (cc[2][0] ^ o20) | (cc[2][1] ^ o21) | (cc[2][2] ^ o22);
            if (!__any(d != 0ULL)) break;
        }
#pragma unroll
        for (int j = 0; j < 3; ++j)
#pragma unroll
            for (int w = 0; w < 3; ++w)
                cmp[(rbase + j) * WPR + w] = cc[j][w];
    }
    __syncthreads();

    // ---- Phase D: compact nonempty comp words, split across waves,
    //      software-pipelined preds gather. facc += (cnt/9 + 1) * log(p).
    for (int k = tid; k < NWORDS; k += NT)
        if (cmp[k] != 0ULL) { int idx = atomicAdd(&cntSh, 1); wlist[idx] = (short)k; }
    __syncthreads();
    {
        const int n = cntSh;
        int i = wv;
        int kc = (i < n) ? (int)wlist[i] : -1;
        float pc = 0.0f;
        if (kc >= 0) pc = pp[(kc << 6) + lane];
        while (kc >= 0) {
            const int i2 = i + NW;
            const int k2 = (i2 < n) ? (int)wlist[i2] : -1;
            float p2 = 0.0f;
            if (k2 >= 0) p2 = pp[(k2 << 6) + lane];   // next load in flight
            u64 P0, P1, P2, P3, mid;
            plane9(cmp, kc, P0, P1, P2, P3, mid);
            if ((mid >> lane) & 1ULL) {
                int ct = (int)((P0 >> lane) & 1ULL)
                       | ((int)((P1 >> lane) & 1ULL) << 1)
                       | ((int)((P2 >> lane) & 1ULL) << 2)
                       | ((int)((P3 >> lane) & 1ULL) << 3);
                facc += ((float)ct * (1.0f / 9.0f) + 1.0f) * __logf(pc + 1e-8f);
            }
            i = i2; kc = k2; pc = p2;
        }
    }

    // ---- Reduce ----
#pragma unroll
    for (int off = 32; off > 0; off >>= 1)
        facc += __shfl_xor(facc, off, 64);
    if (lane == 0) wsum[wv] = (double)facc;
    __syncthreads();
    if (tid == 0)
        atomicAdd(acc, wsum[0] + wsum[1] + wsum[2] + wsum[3]);
}

__global__ void finalize_kernel(const double* __restrict__ acc, float* __restrict__ out)
{
    if (threadIdx.x == 0 && blockIdx.x == 0)
        out[0] = (float)(-acc[0] / (double)((long long)BB * SS * NPIX));
}

extern "C" void kernel_launch(void* const* d_in, const int* in_sizes, int n_in,
                              void* d_out, int out_size, void* d_ws, size_t ws_size,
                              hipStream_t stream)
{
    const float* preds   = (const float*)d_in[0];
    const int*   samples = (const int*)d_in[1];
    double* acc = (double*)d_ws;

    hipMemsetAsync(acc, 0, sizeof(double), stream);
    hipLaunchKernelGGL(cc_fused, dim3(NTASK), dim3(NT), 0, stream,
                       preds, samples, acc);
    hipLaunchKernelGGL(finalize_kernel, dim3(1), dim3(64), 0, stream,
                       acc, (float*)d_out);
}